// Round 1
// baseline (678.851 us; speedup 1.0000x reference)
//
#include <hip/hip_runtime.h>
#include <stdint.h>
#include <stddef.h>

typedef float  f32x4 __attribute__((ext_vector_type(4)));
typedef short  s16x8 __attribute__((ext_vector_type(8)));
typedef short  s16x4 __attribute__((ext_vector_type(4)));

#define LOG2E_F 1.4426950408889634f

static __device__ __forceinline__ unsigned short f2bf(float f) {
    union { float f; unsigned int u; } v; v.f = f;
    unsigned int u = v.u + 0x7FFFu + ((v.u >> 16) & 1u);   // RNE to bf16
    return (unsigned short)(u >> 16);
}
static __device__ __forceinline__ f32x4 mfma16(s16x8 a, s16x8 b, f32x4 c) {
    return __builtin_amdgcn_mfma_f32_16x16x32_bf16(a, b, c, 0, 0, 0);
}

// Precompute bias'[h][m][c][tj] = log2e * bias_table[rel_index[n=tj*16+c][m]][h]
// (float4 over tj at fixed (m,c) -> one vec4 load per (ti,r) in softmax)
__global__ void swin_bias_init(const float* __restrict__ bias_table,
                               const int* __restrict__ rel_index,
                               float* __restrict__ biasW) {
    int t = blockIdx.x * 256 + threadIdx.x;      // 0..16383
    int h = t >> 12, rem = t & 4095;
    int m = rem >> 6, idx = rem & 63;
    int cc = idx >> 2, tj = idx & 3;
    int n = tj * 16 + cc;
    biasW[t] = bias_table[rel_index[n * 64 + m] * 4 + h] * LOG2E_F;
}

// One block = one 8x8 window. 4 waves; wave w handles head w (and 16 qkv/proj cols).
__global__ __launch_bounds__(256, 2) void swin_attn(
    const float* __restrict__ x, const float* __restrict__ qkv_w,
    const float* __restrict__ qkv_b, const float* __restrict__ proj_w,
    const float* __restrict__ proj_b, const float* __restrict__ biasW,
    float* __restrict__ y)
{
    // LDS layout (phase-disjoint aliasing):
    //  [0,32768)  : 4x 8KB P buffers (attn phase)   | aliases xw [0,8192) (phase1)
    //                                                | and out [8192,16384) (phase4+)
    //  [32768,57344): qkv bf16, 64 rows x 384B, 16B-chunk XOR swizzle
    __shared__ __attribute__((aligned(16))) char smem[57344];
    char* Pall = smem;
    char* xwb  = smem;
    char* outb = smem + 8192;
    char* qkvb = smem + 32768;

    const int tid  = threadIdx.x;
    const int w    = tid >> 6;        // wave == head
    const int lane = tid & 63;
    const int g    = lane >> 4;       // k-octet group
    const int c    = lane & 15;       // row/col-within-tile

    // XCD-bijective swizzle (16384 % 8 == 0): contiguous windows per XCD -> L2 merge
    const int swz = ((blockIdx.x & 7) << 11) + (blockIdx.x >> 3);
    const int b  = swz >> 10;
    const int wh = (swz >> 5) & 31;
    const int ww = swz & 31;

    // ---- qkv B-fragments direct from global (L2-hot), kept in regs ----
    const int cb[3] = { w*16, 64 + w*16, 128 + w*16 };   // q,k,v col bases
    s16x8 bwf[3][2];
    #pragma unroll
    for (int t3 = 0; t3 < 3; ++t3) {
        #pragma unroll
        for (int ks = 0; ks < 2; ++ks) {
            s16x8 f;
            #pragma unroll
            for (int i = 0; i < 8; ++i)
                f[i] = (short)f2bf(qkv_w[(ks*32 + g*8 + i)*192 + cb[t3] + c]);
            bwf[t3][ks] = f;
        }
    }

    // ---- stage x window -> LDS bf16 [64 tokens][64 ch], 128B rows, swizzled ----
    {
        const int n  = lane;                       // token = i*8+j
        const int hp = (wh*8 + (n >> 3) + 4) & 255;
        const int wp = (ww*8 + (n & 7) + 4) & 255;
        const float* xp = x + (((size_t)(b*64 + w*16)) << 16) + hp*256 + wp;
        s16x8 p0, p1;
        #pragma unroll
        for (int r = 0; r < 8; ++r) p0[r] = (short)f2bf(xp[(size_t)r << 16]);
        #pragma unroll
        for (int r = 0; r < 8; ++r) p1[r] = (short)f2bf(xp[(size_t)(r + 8) << 16]);
        const int sw = (n & 7) << 4;
        *(s16x8*)(xwb + n*128 + ((w*32 +  0) ^ sw)) = p0;
        *(s16x8*)(xwb + n*128 + ((w*32 + 16) ^ sw)) = p1;
    }
    __syncthreads();

    // ---- qkv GEMM: D[token][col] ; acc C-layout row=g*4+r(+16*mi), col=c ----
    f32x4 acc[4][3];
    #pragma unroll
    for (int t3 = 0; t3 < 3; ++t3) {
        const float bv = qkv_b[cb[t3] + c];
        #pragma unroll
        for (int mi = 0; mi < 4; ++mi) acc[mi][t3] = (f32x4){bv, bv, bv, bv};
    }
    #pragma unroll
    for (int ks = 0; ks < 2; ++ks) {
        #pragma unroll
        for (int mi = 0; mi < 4; ++mi) {
            const int row = mi*16 + c;
            s16x8 a = *(const s16x8*)(xwb + row*128 + ((ks*64 + g*16) ^ ((row & 7) << 4)));
            #pragma unroll
            for (int t3 = 0; t3 < 3; ++t3)
                acc[mi][t3] = mfma16(a, bwf[t3][ks], acc[mi][t3]);
        }
    }
    // write q,k,v (bf16) to LDS: rows 384B, chunk-swizzled
    #pragma unroll
    for (int mi = 0; mi < 4; ++mi) {
        #pragma unroll
        for (int t3 = 0; t3 < 3; ++t3) {
            #pragma unroll
            for (int r = 0; r < 4; ++r) {
                const int row = mi*16 + g*4 + r;
                *(unsigned short*)(qkvb + row*384 + ((2*(cb[t3] + c)) ^ ((row & 7) << 4)))
                    = f2bf(acc[mi][t3][r]);
            }
        }
    }
    __syncthreads();   // xw reads done; P region (aliases xw) may now be written

    // ---- S^T = K * Q^T  (swapped so softmax reduce is cheap) ----
    // A=K: row=m=ti*16+c, k=d ; B=Q: col=n=tj*16+c, k=d ; d>=16 zero-padded
    s16x8 ak[4], bq[4];
    #pragma unroll
    for (int ti = 0; ti < 4; ++ti) {
        s16x8 fk = (s16x8)0, fq = (s16x8)0;
        if (g < 2) {
            const int row = ti*16 + c;
            const int sw  = (row & 7) << 4;
            fk = *(const s16x8*)(qkvb + row*384 + ((128 + w*32 + g*16) ^ sw));
            fq = *(const s16x8*)(qkvb + row*384 + ((      w*32 + g*16) ^ sw));
        }
        ak[ti] = fk; bq[ti] = fq;
    }
    f32x4 s[4][4];   // [ti(m-tile)][tj(n-tile)] : row=m, col=n
    #pragma unroll
    for (int ti = 0; ti < 4; ++ti)
        #pragma unroll
        for (int tj = 0; tj < 4; ++tj)
            s[ti][tj] = mfma16(ak[ti], bq[tj], (f32x4){0.f, 0.f, 0.f, 0.f});

    // l = S*scale*log2e + bias'  (bias' pre-scaled by log2e)
    const float SCL = 0.25f * LOG2E_F;
    #pragma unroll
    for (int ti = 0; ti < 4; ++ti) {
        #pragma unroll
        for (int r = 0; r < 4; ++r) {
            const int m = ti*16 + g*4 + r;
            f32x4 bb = *(const f32x4*)(biasW + (((w*64 + m)*16 + c) << 2));
            #pragma unroll
            for (int tj = 0; tj < 4; ++tj)
                s[ti][tj][r] = s[ti][tj][r] * SCL + bb[tj];
        }
    }

    // ---- softmax over m (16 lane-local + shfl_xor 16/32), normalize, pack P ----
    char* Pw = Pall + w*8192;    // P[n][m] bf16, 128B rows, swizzled
    #pragma unroll
    for (int tj = 0; tj < 4; ++tj) {
        float mx = -3.0e38f;
        #pragma unroll
        for (int ti = 0; ti < 4; ++ti)
            #pragma unroll
            for (int r = 0; r < 4; ++r) mx = fmaxf(mx, s[ti][tj][r]);
        mx = fmaxf(mx, __shfl_xor(mx, 16));
        mx = fmaxf(mx, __shfl_xor(mx, 32));
        float sum = 0.f;
        #pragma unroll
        for (int ti = 0; ti < 4; ++ti)
            #pragma unroll
            for (int r = 0; r < 4; ++r) {
                const float p = exp2f(s[ti][tj][r] - mx);
                s[ti][tj][r] = p; sum += p;
            }
        sum += __shfl_xor(sum, 16);
        sum += __shfl_xor(sum, 32);
        const float rs = 1.0f / sum;
        const int n  = tj*16 + c;
        const int sw = (n & 7) << 4;
        #pragma unroll
        for (int ti = 0; ti < 4; ++ti) {
            s16x4 pk;
            #pragma unroll
            for (int r = 0; r < 4; ++r) pk[r] = (short)f2bf(s[ti][tj][r] * rs);
            *(s16x4*)(Pw + n*128 + ((ti*32 + g*8) ^ sw)) = pk;   // m0=ti*16+g*4
        }
    }

    // ---- PV: out[n][d] = P[n][m] V[m][d] ----
    f32x4 o4[4];
    #pragma unroll
    for (int mi = 0; mi < 4; ++mi) o4[mi] = (f32x4){0.f, 0.f, 0.f, 0.f};
    #pragma unroll
    for (int ks = 0; ks < 2; ++ks) {
        s16x8 bv;                                  // V col-read: d=c, k=m
        #pragma unroll
        for (int i = 0; i < 8; ++i) {
            const int m = ks*32 + g*8 + i;
            bv[i] = *(const unsigned short*)(qkvb + m*384 + ((256 + w*32 + 2*c) ^ ((m & 7) << 4)));
        }
        #pragma unroll
        for (int mi = 0; mi < 4; ++mi) {
            const int row = mi*16 + c;
            s16x8 a = *(const s16x8*)(Pw + row*128 + ((ks*64 + g*16) ^ ((row & 7) << 4)));
            o4[mi] = mfma16(a, bv, o4[mi]);
        }
    }
    __syncthreads();   // all PV reads done before out (aliases wave1 P) is written

    // ---- stage attention output bf16 [64][64] for proj ----
    #pragma unroll
    for (int mi = 0; mi < 4; ++mi) {
        #pragma unroll
        for (int r = 0; r < 4; ++r) {
            const int row = mi*16 + g*4 + r;
            *(unsigned short*)(outb + row*128 + ((2*(w*16 + c)) ^ ((row & 7) << 4)))
                = f2bf(o4[mi][r]);
        }
    }
    __syncthreads();

    // ---- proj: y_tok[n][o] = out[n][ch] * proj_w[ch][o] ----
    f32x4 po[4];
    {
        const float pb = proj_b[w*16 + c];
        #pragma unroll
        for (int mi = 0; mi < 4; ++mi) po[mi] = (f32x4){pb, pb, pb, pb};
    }
    #pragma unroll
    for (int ks = 0; ks < 2; ++ks) {
        s16x8 bp;
        #pragma unroll
        for (int i = 0; i < 8; ++i)
            bp[i] = (short)f2bf(proj_w[(ks*32 + g*8 + i)*64 + w*16 + c]);
        #pragma unroll
        for (int mi = 0; mi < 4; ++mi) {
            const int row = mi*16 + c;
            s16x8 a = *(const s16x8*)(outb + row*128 + ((ks*64 + g*16) ^ ((row & 7) << 4)));
            po[mi] = mfma16(a, bp, po[mi]);
        }
    }

    // ---- store: lane's 4 acc regs = 4 consecutive wp pixels -> float4 ----
    float* yb = y + (((size_t)(b*64 + w*16 + c)) << 16);
    #pragma unroll
    for (int mi = 0; mi < 4; ++mi) {
        const int i0 = 2*mi + (g >> 1);
        const int j0 = (g & 1) * 4;
        const int hp = (wh*8 + i0 + 4) & 255;
        const int wp = (ww*8 + j0 + 4) & 255;
        *(f32x4*)(yb + hp*256 + wp) = po[mi];
    }
}

extern "C" void kernel_launch(void* const* d_in, const int* in_sizes, int n_in,
                              void* d_out, int out_size, void* d_ws, size_t ws_size,
                              hipStream_t stream) {
    const float* x          = (const float*)d_in[0];
    const float* qkv_w      = (const float*)d_in[1];
    const float* qkv_b      = (const float*)d_in[2];
    const float* proj_w     = (const float*)d_in[3];
    const float* proj_b     = (const float*)d_in[4];
    const float* bias_table = (const float*)d_in[5];
    const int*   rel_index  = (const int*)d_in[6];
    float* yout  = (float*)d_out;
    float* biasW = (float*)d_ws;    // 16384 floats = 64 KB

    swin_bias_init<<<64, 256, 0, stream>>>(bias_table, rel_index, biasW);
    swin_attn<<<16384, 256, 0, stream>>>(x, qkv_w, qkv_b, proj_w, proj_b, biasW, yout);
}